// Round 5
// baseline (626.042 us; speedup 1.0000x reference)
//
#include <hip/hip_runtime.h>
#include <stdint.h>

// ---------------------------------------------------------------------------
// OrthoLinear: out[b,s,o] = sum_k x[b,s,k] * (dequant(base_packed,scales)[o,k]
//                                             + w_ortho[o,k])
// M = B*S = 8192, N = OUT = 4096, K = IN = 4096, fp32 in/out.
// R8: uniform 4-phase BK=64 single-buffer pipeline (from R4's verified parts).
//   - LDS: single [256][64] bf16 buffer per matrix (32 KB each, 64 KB total).
//     Row = 128 B; store chunk' = chunk ^ (row&7); staging pre-swizzles the
//     global source (gload_lds dest linear), frag reads apply the same XOR.
//     Bank-uniform under full-wave and half-wave models (16x16 frag family
//     = R4's, measured 0 conflicts).
//   - Wave tiles are SPLIT halves: wave wm rows = wm*64+[0,64) U 128+wm*64+
//     [0,64); wave wn cols = wn*32+[0,32) U 128+wn*32+[0,32). So staging
//     half-tiles (A rows[0,128)/[128,256), B cols same) are each consumed by
//     exactly ONE phase -> in-place restaging is race-free (stage issued one
//     barrier-pair after the region's last reader phase).
//   - Per K-tile T, 4 phases {reads; 2 gload_lds; vmcnt(4); bar; lgkm0;
//     prio1; 16 MFMA; prio0; bar}:
//       ph1: read A-h0 (8 b128)          stage B0(T+1)  mfma miH0 x niH0 (bb regs)
//       ph2: read B-h1 (4)               stage A0(T+1)  mfma miH0 x niH1
//       ph3: read A-h1 (8)               stage B1(T+1)  mfma miH1 x niH1
//       ph4: read B0(T+1)->regs (4)      stage A1(T+1)  mfma miH1 x niH0 (bb regs)
//     Every load pair is needed exactly 2 phases after issue -> uniform
//     vmcnt(4), never draining. B0 frags carried in regs across the tile
//     boundary (bbA/bbB double naming, static indexing).
//   - Liveness audit: A-h0 last read ph1 / staged ph2; B-h1 ph2/ph3; A-h1
//     ph3/ph4; B-h0 last read T-1 ph4 / staged T ph1. One barrier-pair
//     between every (last read, overwrite). Cross-wave completion: each
//     wave's vmcnt(4) bounds its own loads; barrier pairs publish.
// ---------------------------------------------------------------------------

#define M_TOTAL 8192
#define N_TOTAL 4096
#define K_TOTAL 4096

typedef __attribute__((ext_vector_type(8)))  __bf16          bf16x8;   // MFMA A/B frag
typedef __attribute__((ext_vector_type(4)))  float           floatx4;  // MFMA C/D frag
typedef __attribute__((ext_vector_type(8)))  unsigned short  ushort8;
typedef __attribute__((ext_vector_type(4)))  float           f32x4;
typedef __attribute__((ext_vector_type(4)))  int             intx4;

// fp32 -> bf16 round-to-nearest-even (data has no NaN)
__device__ __forceinline__ unsigned short f2bf(float f) {
    union { float f; uint32_t u; } c; c.f = f;
    uint32_t u = c.u + 0x7FFFu + ((c.u >> 16) & 1u);
    return (unsigned short)(u >> 16);
}

// ---------------------------------------------------------------------------
// Merged prep (byte-identical since R3 — control variable).
// ---------------------------------------------------------------------------
#define CVT_BLOCKS 16384
#define DEQ_BLOCKS 8192

__global__ __launch_bounds__(256) void prep_kernel(
    const float* __restrict__ x,        // [M, K] fp32
    const int*   __restrict__ packed,   // [N, K/2] nibble-packed
    const float* __restrict__ scales,   // [N]
    const float* __restrict__ ortho,    // [N, K] fp32
    unsigned short* __restrict__ xb,    // [M, K] bf16 out
    unsigned short* __restrict__ wb)    // [N, K] bf16 out
{
    const int blk = blockIdx.x;
    if (blk < CVT_BLOCKS) {
        const size_t t = (size_t)blk * 256 + threadIdx.x;
        const f32x4* xv = (const f32x4*)x;
        f32x4 v0 = xv[2 * t];
        f32x4 v1 = xv[2 * t + 1];
        ushort8 r;
        r[0] = f2bf(v0[0]); r[1] = f2bf(v0[1]); r[2] = f2bf(v0[2]); r[3] = f2bf(v0[3]);
        r[4] = f2bf(v1[0]); r[5] = f2bf(v1[1]); r[6] = f2bf(v1[2]); r[7] = f2bf(v1[3]);
        ((ushort8*)xb)[t] = r;
    } else {
        const int t  = (blk - CVT_BLOCKS) * 256 + threadIdx.x;  // 0 .. N*(K/2)/4
        const int o  = t >> 9;                                  // 512 threads/row
        const int jp = (t & 511) << 2;                          // packed col base
        intx4 p = *(const intx4*)(packed + (size_t)o * (K_TOTAL / 2) + jp);
        const float s = scales[o];
        const size_t base = (size_t)o * K_TOTAL + (size_t)jp * 2;
        f32x4 g0 = *(const f32x4*)(ortho + base);
        f32x4 g1 = *(const f32x4*)(ortho + base + 4);
        float g[8] = { g0[0], g0[1], g0[2], g0[3], g1[0], g1[1], g1[2], g1[3] };
        ushort8 r;
#pragma unroll
        for (int i = 0; i < 4; ++i) {
            int pi = p[i];
            float lo = (float)((pi & 0xF) - 8) * s + g[2 * i];
            float hi = (float)(((pi >> 4) & 0xF) - 8) * s + g[2 * i + 1];
            r[2 * i]     = f2bf(lo);
            r[2 * i + 1] = f2bf(hi);
        }
        *(ushort8*)(wb + base) = r;
    }
}

// ---------------------------------------------------------------------------
// GEMM: C[M,N] = A[M,K](bf16) @ B[N,K](bf16)^T, fp32 accumulate.
// ---------------------------------------------------------------------------
__device__ __forceinline__ void async16(const void* g, void* l) {
    __builtin_amdgcn_global_load_lds(
        (__attribute__((address_space(1))) void*)(g),
        (__attribute__((address_space(3))) void*)(l),
        16, 0, 0);
}

__global__ __launch_bounds__(512, 2) void gemm256_kernel(
    const unsigned short* __restrict__ A,   // [M,K] bf16
    const unsigned short* __restrict__ Bm,  // [N,K] bf16
    float* __restrict__ C)                  // [M,N] fp32
{
    // Single-buffered [256 rows][64 cols] bf16 per matrix = 32 KB each.
    __shared__ __attribute__((aligned(16))) unsigned short As[16384];
    __shared__ __attribute__((aligned(16))) unsigned short Bs[16384];

    const int tid  = threadIdx.x;
    const int wave = tid >> 6;
    const int lane = tid & 63;
    const int quad = lane >> 4;
    const int r16  = lane & 15;
    const int s8   = r16 & 7;        // row swizzle term (bases ≡ 0 mod 16)
    const int wm   = wave >> 2;      // 0..1
    const int wn   = wave & 3;       // 0..3

    const int row0 = blockIdx.y * 256;   // M origin
    const int col0 = blockIdx.x * 256;   // N origin

    // --- staging: half-tile [128 rows][64 cols] = 16 KB; wave stages 2 KB as
    // 2 x gload_lds. Linear dest: (wave*128 + j*64 + lane)*16 B ->
    // dest row = wave*16 + j*8 + (lane>>3), dest chunk = lane&7.
    // Source chunk = (lane&7) ^ (row&7) = (lane&7) ^ ((lane>>3)&7).
    const int w16l  = wave * 16 + (lane >> 3);
    const int c_src = (lane & 7) ^ ((lane >> 3) & 7);
    const unsigned short* agA0 = A  + (size_t)(row0 + w16l) * K_TOTAL + c_src * 8;
    const unsigned short* agA1 = agA0 + (size_t)128 * K_TOTAL;
    const unsigned short* bgB0 = Bm + (size_t)(col0 + w16l) * K_TOTAL + c_src * 8;
    const unsigned short* bgB1 = bgB0 + (size_t)128 * K_TOTAL;
    unsigned short* dA0 = As + wave * 1024;          // h0: rows [0,128)
    unsigned short* dA1 = As + 8192 + wave * 1024;   // h1: rows [128,256)
    unsigned short* dB0 = Bs + wave * 1024;
    unsigned short* dB1 = Bs + 8192 + wave * 1024;

#define STG(dst, src, T) do { \
    async16((src) + (size_t)(T) * 64, (dst)); \
    async16((src) + (size_t)(T) * 64 + (size_t)8 * K_TOTAL, (dst) + 512); } while (0)

    // --- fragment reads: addr = row*64 + ((kk*4+quad)^s8)*8 elems.
    const int ck0 = ((0 + quad) ^ s8) * 8;   // kk=0 chunk term
    const int ck1 = ((4 + quad) ^ s8) * 8;   // kk=1 chunk term
    // mi 0..3 -> rows wm*64+mi*16; mi 4..7 -> 128+wm*64+(mi-4)*16 (all +r16).
#define AROW(mi) ((((mi) < 4 ? wm * 64 + (mi) * 16 : 128 + wm * 64 + ((mi) - 4) * 16) + r16) * 64)
#define BROW(ni) ((((ni) < 2 ? wn * 32 + (ni) * 16 : 128 + wn * 32 + ((ni) - 2) * 16) + r16) * 64)
#define LDSA(mi, ckk) (*(const bf16x8*)(As + AROW(mi) + (ckk)))
#define LDSB(ni, ckk) (*(const bf16x8*)(Bs + BROW(ni) + (ckk)))

    floatx4 acc[8][4] = {};

#define MM(mi, ni, af, bf) \
    acc[mi][ni] = __builtin_amdgcn_mfma_f32_16x16x32_bf16(af, bf, acc[mi][ni], 0, 0, 0);
// 8 MFMA: mi block (m0..m0+3) x ni pair (n0,n0+1), one kk.
#define C8(m0, aA, aB, aC, aD, n0, bX, bY) \
    MM(m0 + 0, n0, aA, bX) MM(m0 + 0, n0 + 1, aA, bY) \
    MM(m0 + 1, n0, aB, bX) MM(m0 + 1, n0 + 1, aB, bY) \
    MM(m0 + 2, n0, aC, bX) MM(m0 + 2, n0 + 1, aC, bY) \
    MM(m0 + 3, n0, aD, bX) MM(m0 + 3, n0 + 1, aD, bY)

#define BAR    __builtin_amdgcn_s_barrier()
#define LGKM0  asm volatile("s_waitcnt lgkmcnt(0)")
#define VM4    asm volatile("s_waitcnt vmcnt(4)")
#define PRIO1  __builtin_amdgcn_s_setprio(1)
#define PRIO0  __builtin_amdgcn_s_setprio(0)
#define SCHED0 __builtin_amdgcn_sched_barrier(0)

    // B0 frags (ni 0,1 x kk 0,1) carried in regs across the tile boundary.
    bf16x8 bbAk0_0, bbAk0_1, bbAk1_0, bbAk1_1;
    bf16x8 bbBk0_0, bbBk0_1, bbBk1_0, bbBk1_1;

// One K=64 tile: CUR = bb set holding B0(T) (read last tile's ph4);
// NXT = bb set to fill with B0(T+1) in ph4. DOSTG stages tile T+1.
#define TILE(T, CUR, NXT, DOSTG) do { \
    /* ph1: A-h0 reads; stage B0(T+1); mfma miH0 x niH0 */ \
    bf16x8 a0k0_0 = LDSA(0, ck0), a0k0_1 = LDSA(1, ck0), a0k0_2 = LDSA(2, ck0), a0k0_3 = LDSA(3, ck0); \
    bf16x8 a0k1_0 = LDSA(0, ck1), a0k1_1 = LDSA(1, ck1), a0k1_2 = LDSA(2, ck1), a0k1_3 = LDSA(3, ck1); \
    if (DOSTG) STG(dB0, bgB0, (T) + 1); \
    VM4; BAR; LGKM0; PRIO1; \
    C8(0, a0k0_0, a0k0_1, a0k0_2, a0k0_3, 0, bb##CUR##k0_0, bb##CUR##k0_1) \
    C8(0, a0k1_0, a0k1_1, a0k1_2, a0k1_3, 0, bb##CUR##k1_0, bb##CUR##k1_1) \
    PRIO0; BAR; SCHED0; \
    /* ph2: B-h1 reads; stage A0(T+1); mfma miH0 x niH1 */ \
    bf16x8 b1k0_2 = LDSB(2, ck0), b1k0_3 = LDSB(3, ck0); \
    bf16x8 b1k1_2 = LDSB(2, ck1), b1k1_3 = LDSB(3, ck1); \
    if (DOSTG) STG(dA0, agA0, (T) + 1); \
    VM4; BAR; LGKM0; PRIO1; \
    C8(0, a0k0_0, a0k0_1, a0k0_2, a0k0_3, 2, b1k0_2, b1k0_3) \
    C8(0, a0k1_0, a0k1_1, a0k1_2, a0k1_3, 2, b1k1_2, b1k1_3) \
    PRIO0; BAR; SCHED0; \
    /* ph3: A-h1 reads; stage B1(T+1); mfma miH1 x niH1 */ \
    bf16x8 a1k0_0 = LDSA(4, ck0), a1k0_1 = LDSA(5, ck0), a1k0_2 = LDSA(6, ck0), a1k0_3 = LDSA(7, ck0); \
    bf16x8 a1k1_0 = LDSA(4, ck1), a1k1_1 = LDSA(5, ck1), a1k1_2 = LDSA(6, ck1), a1k1_3 = LDSA(7, ck1); \
    if (DOSTG) STG(dB1, bgB1, (T) + 1); \
    VM4; BAR; LGKM0; PRIO1; \
    C8(4, a1k0_0, a1k0_1, a1k0_2, a1k0_3, 2, b1k0_2, b1k0_3) \
    C8(4, a1k1_0, a1k1_1, a1k1_2, a1k1_3, 2, b1k1_2, b1k1_3) \
    PRIO0; BAR; SCHED0; \
    /* ph4: B0(T+1) -> NXT regs; stage A1(T+1); mfma miH1 x niH0 */ \
    bb##NXT##k0_0 = LDSB(0, ck0); bb##NXT##k0_1 = LDSB(1, ck0); \
    bb##NXT##k1_0 = LDSB(0, ck1); bb##NXT##k1_1 = LDSB(1, ck1); \
    if (DOSTG) STG(dA1, agA1, (T) + 1); \
    VM4; BAR; LGKM0; PRIO1; \
    C8(4, a1k0_0, a1k0_1, a1k0_2, a1k0_3, 0, bb##CUR##k0_0, bb##CUR##k0_1) \
    C8(4, a1k1_0, a1k1_1, a1k1_2, a1k1_3, 0, bb##CUR##k1_0, bb##CUR##k1_1) \
    PRIO0; BAR; SCHED0; \
} while (0)

// Last tile: no stages, no next-B0 reads; waits cover the final pairs:
// ph1 wait -> B1(63) (newer: A1(63) = 2) => vmcnt(2); ph2 wait -> A1(63)
// (nothing newer) => vmcnt(0); ph3/ph4 need no vm waits.
#define TAIL(CUR) do { \
    bf16x8 a0k0_0 = LDSA(0, ck0), a0k0_1 = LDSA(1, ck0), a0k0_2 = LDSA(2, ck0), a0k0_3 = LDSA(3, ck0); \
    bf16x8 a0k1_0 = LDSA(0, ck1), a0k1_1 = LDSA(1, ck1), a0k1_2 = LDSA(2, ck1), a0k1_3 = LDSA(3, ck1); \
    asm volatile("s_waitcnt vmcnt(2)"); BAR; LGKM0; PRIO1; \
    C8(0, a0k0_0, a0k0_1, a0k0_2, a0k0_3, 0, bb##CUR##k0_0, bb##CUR##k0_1) \
    C8(0, a0k1_0, a0k1_1, a0k1_2, a0k1_3, 0, bb##CUR##k1_0, bb##CUR##k1_1) \
    PRIO0; BAR; SCHED0; \
    bf16x8 b1k0_2 = LDSB(2, ck0), b1k0_3 = LDSB(3, ck0); \
    bf16x8 b1k1_2 = LDSB(2, ck1), b1k1_3 = LDSB(3, ck1); \
    asm volatile("s_waitcnt vmcnt(0)"); BAR; LGKM0; PRIO1; \
    C8(0, a0k0_0, a0k0_1, a0k0_2, a0k0_3, 2, b1k0_2, b1k0_3) \
    C8(0, a0k1_0, a0k1_1, a0k1_2, a0k1_3, 2, b1k1_2, b1k1_3) \
    PRIO0; BAR; SCHED0; \
    bf16x8 a1k0_0 = LDSA(4, ck0), a1k0_1 = LDSA(5, ck0), a1k0_2 = LDSA(6, ck0), a1k0_3 = LDSA(7, ck0); \
    bf16x8 a1k1_0 = LDSA(4, ck1), a1k1_1 = LDSA(5, ck1), a1k1_2 = LDSA(6, ck1), a1k1_3 = LDSA(7, ck1); \
    BAR; LGKM0; PRIO1; \
    C8(4, a1k0_0, a1k0_1, a1k0_2, a1k0_3, 2, b1k0_2, b1k0_3) \
    C8(4, a1k1_0, a1k1_1, a1k1_2, a1k1_3, 2, b1k1_2, b1k1_3) \
    C8(4, a1k0_0, a1k0_1, a1k0_2, a1k0_3, 0, bb##CUR##k0_0, bb##CUR##k0_1) \
    C8(4, a1k1_0, a1k1_1, a1k1_2, a1k1_3, 0, bb##CUR##k1_0, bb##CUR##k1_1) \
    PRIO0; \
} while (0)

    // Prologue: stage tile 0 in the steady-state program order [B0,A0,B1,A1],
    // drain once, publish, read B0(0) into bbA.
    STG(dB0, bgB0, 0); STG(dA0, agA0, 0); STG(dB1, bgB1, 0); STG(dA1, agA1, 0);
    asm volatile("s_waitcnt vmcnt(0)");
    BAR; SCHED0;
    bbAk0_0 = LDSB(0, ck0); bbAk0_1 = LDSB(1, ck0);
    bbAk1_0 = LDSB(0, ck1); bbAk1_1 = LDSB(1, ck1);

#pragma unroll 1
    for (int T = 0; T < 62; T += 2) {
        TILE(T,     A, B, 1);
        TILE(T + 1, B, A, 1);
    }
    TILE(62, A, B, 1);
    TAIL(B);

#undef TILE
#undef TAIL
#undef C8
#undef MM
#undef LDSA
#undef LDSB
#undef AROW
#undef BROW
#undef STG

    // Epilogue. C/D layout (m89/m91-verified): col = lane&15, row = quad*4+reg.
#pragma unroll
    for (int mi = 0; mi < 8; ++mi) {
        const int r = row0 + (mi < 4 ? wm * 64 + mi * 16 : 128 + wm * 64 + (mi - 4) * 16) + quad * 4;
#pragma unroll
        for (int ni = 0; ni < 4; ++ni) {
            const int c = col0 + (ni < 2 ? wn * 32 + ni * 16 : 128 + wn * 32 + (ni - 2) * 16) + r16;
#pragma unroll
            for (int i = 0; i < 4; ++i)
                C[(size_t)(r + i) * N_TOTAL + c] = acc[mi][ni][i];
        }
    }
}

// ---------------------------------------------------------------------------
extern "C" void kernel_launch(void* const* d_in, const int* in_sizes, int n_in,
                              void* d_out, int out_size, void* d_ws, size_t ws_size,
                              hipStream_t stream) {
    const float* x      = (const float*)d_in[0];   // [4,2048,4096] fp32
    const int*   packed = (const int*)d_in[1];     // [4096,2048] int32
    const float* scales = (const float*)d_in[2];   // [4096,1] fp32
    const float* ortho  = (const float*)d_in[3];   // [4096,4096] fp32
    float*       out    = (float*)d_out;           // [4,2048,4096] fp32

    // Workspace layout: Xb (bf16, 64 MB) | Wb (bf16, 32 MB) = 96 MB total
    unsigned short* Xb = (unsigned short*)d_ws;
    unsigned short* Wb = (unsigned short*)((char*)d_ws + (size_t)M_TOTAL * K_TOTAL * 2);

    prep_kernel<<<CVT_BLOCKS + DEQ_BLOCKS, 256, 0, stream>>>(x, packed, scales, ortho, Xb, Wb);

    dim3 grid(N_TOTAL / 256, M_TOTAL / 256);  // (16, 32) = 512 blocks
    gemm256_kernel<<<grid, 512, 0, stream>>>(Xb, Wb, out);
}

// Round 7
// 551.168 us; speedup vs baseline: 1.1358x; 1.1358x over previous
//
#include <hip/hip_runtime.h>
#include <stdint.h>

// ---------------------------------------------------------------------------
// OrthoLinear: out[b,s,o] = sum_k x[b,s,k] * (dequant(base_packed,scales)[o,k]
//                                             + w_ortho[o,k])
// M = B*S = 8192, N = OUT = 4096, K = IN = 4096, fp32 in/out.
// R9 = R4 (verified 257us best) + cross-slice ds_read pipelining.
//   (Resubmission of round-5 kernel: round-6 bench was an infra failure —
//   container acquisition died; kernel re-audited for hang/fault: LDS bounds
//   exact, uniform barriers, vmcnt waits satisfiable, regs ~230 < 256.)
//   R4's stall (calibrated): per K=32 slice, ALL waves read (96 b128 on the
//   CU LDS port ~1130cyc, MFMA idle) then ALL waves MFMA (~1240cyc, LDS
//   idle) -> sum 2370 ~= measured 2410 cyc. Fix: prefetch next slice's
//   B(4)+A0..3(4) frags DURING this slice's MFMA cluster; read A4..7
//   in-slice (compiler counted-lgkm wait hides under first 16 MFMA).
//   NO hand lgkmcnt(0) anywhere (that serialized R7).
//   Ring (4 slots/matrix) retimed: stage at slice s targets slot (s+3)&3;
//   vmcnt(4) at EVERY slice end -> batch(s-1) (slot s+2) complete at
//   bar(end s) -> prefetch reads of slot s+2 during slice s+1 are safe.
//   Overwrite audit: stage at slice s hits slot (s-1)&3; its last readers
//   (prefetch at s-2, in-slice x at s-1) retire into regs before
//   bar(end s-1) (compiler waits precede the consuming MFMAs). One barrier
//   per slice suffices: readers retire reads before reaching their barrier.
//   Everything else (staging map, chunk-XOR swizzle, frag formulas, C/D
//   layout, accumulation order) byte-identical to R4 -> same absmax.
// ---------------------------------------------------------------------------

#define M_TOTAL 8192
#define N_TOTAL 4096
#define K_TOTAL 4096

typedef __attribute__((ext_vector_type(8)))  __bf16          bf16x8;   // MFMA A/B frag (4 VGPRs)
typedef __attribute__((ext_vector_type(4)))  float           floatx4;  // MFMA C/D frag
typedef __attribute__((ext_vector_type(8)))  unsigned short  ushort8;
typedef __attribute__((ext_vector_type(4)))  float           f32x4;
typedef __attribute__((ext_vector_type(4)))  int             intx4;

// fp32 -> bf16 round-to-nearest-even (data has no NaN)
__device__ __forceinline__ unsigned short f2bf(float f) {
    union { float f; uint32_t u; } c; c.f = f;
    uint32_t u = c.u + 0x7FFFu + ((c.u >> 16) & 1u);
    return (unsigned short)(u >> 16);
}

// ---------------------------------------------------------------------------
// Merged prep (byte-identical since R3 — control variable).
// ---------------------------------------------------------------------------
#define CVT_BLOCKS 16384
#define DEQ_BLOCKS 8192

__global__ __launch_bounds__(256) void prep_kernel(
    const float* __restrict__ x,        // [M, K] fp32
    const int*   __restrict__ packed,   // [N, K/2] nibble-packed
    const float* __restrict__ scales,   // [N]
    const float* __restrict__ ortho,    // [N, K] fp32
    unsigned short* __restrict__ xb,    // [M, K] bf16 out
    unsigned short* __restrict__ wb)    // [N, K] bf16 out
{
    const int blk = blockIdx.x;
    if (blk < CVT_BLOCKS) {
        const size_t t = (size_t)blk * 256 + threadIdx.x;
        const f32x4* xv = (const f32x4*)x;
        f32x4 v0 = xv[2 * t];
        f32x4 v1 = xv[2 * t + 1];
        ushort8 r;
        r[0] = f2bf(v0[0]); r[1] = f2bf(v0[1]); r[2] = f2bf(v0[2]); r[3] = f2bf(v0[3]);
        r[4] = f2bf(v1[0]); r[5] = f2bf(v1[1]); r[6] = f2bf(v1[2]); r[7] = f2bf(v1[3]);
        ((ushort8*)xb)[t] = r;
    } else {
        const int t  = (blk - CVT_BLOCKS) * 256 + threadIdx.x;  // 0 .. N*(K/2)/4
        const int o  = t >> 9;                                  // 512 threads/row
        const int jp = (t & 511) << 2;                          // packed col base
        intx4 p = *(const intx4*)(packed + (size_t)o * (K_TOTAL / 2) + jp);
        const float s = scales[o];
        const size_t base = (size_t)o * K_TOTAL + (size_t)jp * 2;
        f32x4 g0 = *(const f32x4*)(ortho + base);
        f32x4 g1 = *(const f32x4*)(ortho + base + 4);
        float g[8] = { g0[0], g0[1], g0[2], g0[3], g1[0], g1[1], g1[2], g1[3] };
        ushort8 r;
#pragma unroll
        for (int i = 0; i < 4; ++i) {
            int pi = p[i];
            float lo = (float)((pi & 0xF) - 8) * s + g[2 * i];
            float hi = (float)(((pi >> 4) & 0xF) - 8) * s + g[2 * i + 1];
            r[2 * i]     = f2bf(lo);
            r[2 * i + 1] = f2bf(hi);
        }
        *(ushort8*)(wb + base) = r;
    }
}

// ---------------------------------------------------------------------------
// GEMM: C[M,N] = A[M,K](bf16) @ B[N,K](bf16)^T, fp32 accumulate.
// 256x256 tile, 8 waves (2M x 4N), per-wave 128x64, acc[8][4] of 16x16.
// 4-deep ring of K=32 slices; one barrier/slice; cross-slice read pipeline.
// ---------------------------------------------------------------------------
__device__ __forceinline__ void async16(const void* g, void* l) {
    __builtin_amdgcn_global_load_lds(
        (__attribute__((address_space(1))) void*)(g),
        (__attribute__((address_space(3))) void*)(l),
        16, 0, 0);
}

__global__ __launch_bounds__(512, 2) void gemm256_kernel(
    const unsigned short* __restrict__ A,   // [M,K] bf16
    const unsigned short* __restrict__ Bm,  // [N,K] bf16
    float* __restrict__ C)                  // [M,N] fp32
{
    // 4 ring slots per matrix; slot = [256 rows][32 cols] bf16 = 8192 elems.
    __shared__ __attribute__((aligned(16))) unsigned short As[4 * 8192];
    __shared__ __attribute__((aligned(16))) unsigned short Bs[4 * 8192];

    const int tid  = threadIdx.x;
    const int wave = tid >> 6;
    const int lane = tid & 63;
    const int quad = lane >> 4;
    const int r16  = lane & 15;
    const int wm   = wave >> 2;      // 0..1  : wave M index (128 rows each)
    const int wn   = wave & 3;       // 0..3  : wave N index (64 cols each)

    const int row0 = blockIdx.y * 256;   // M origin
    const int col0 = blockIdx.x * 256;   // N origin

    // --- staging source (pre-swizzled: gload_lds dest is linear base+lane*16)
    // instruction covers 128 rows x 32 cols (8 KB); thread t -> row t>>2,
    // dest chunk t&3; source chunk = (t&3) ^ ((row>>1)&3) = (t&3)^((t>>3)&3).
    const int sr = tid >> 2;                       // 0..127
    const int cs = (tid & 3) ^ ((tid >> 3) & 3);   // swizzled source chunk
    const unsigned short* ag0 = A  + (size_t)(row0 + sr) * K_TOTAL + cs * 8;
    const unsigned short* ag1 = ag0 + (size_t)128 * K_TOTAL;
    const unsigned short* bg0 = Bm + (size_t)(col0 + sr) * K_TOTAL + cs * 8;
    const unsigned short* bg1 = bg0 + (size_t)128 * K_TOTAL;

    unsigned short* AsW = As + wave * 512;   // wave's 1 KB slice of each 8 KB half
    unsigned short* BsW = Bs + wave * 512;

#define STAGE_A(slot, kk) do { \
    async16(ag0 + (kk), AsW + (slot) * 8192); \
    async16(ag1 + (kk), AsW + (slot) * 8192 + 4096); } while (0)
#define STAGE_B(slot, kk) do { \
    async16(bg0 + (kk), BsW + (slot) * 8192); \
    async16(bg1 + (kk), BsW + (slot) * 8192 + 4096); } while (0)

    // --- fragment reads (R4-verified, 0 conflicts): row stride 32 elems;
    // chunk read back through the same XOR; frag row offsets ≡0 mod period.
    const int swz   = (r16 >> 1) & 3;
    const int a_ofs = (wm * 128 + r16) * 32 + ((quad ^ swz) << 3);
    const int b_ofs = (wn * 64  + r16) * 32 + ((quad ^ swz) << 3);

#define LDA(slot, m) (*(const bf16x8*)(As + (slot) * 8192 + a_ofs + (m) * 512))
#define LDB(slot, n) (*(const bf16x8*)(Bs + (slot) * 8192 + b_ofs + (n) * 512))

    floatx4 acc[8][4] = {};

    // Double-buffered prefetch sets (E/O by slice parity): B 4 + A rows 0..3.
    bf16x8 bE0, bE1, bE2, bE3, aE0, aE1, aE2, aE3;
    bf16x8 bO0, bO1, bO2, bO3, aO0, aO1, aO2, aO3;

#define MROW(mi, areg, S) \
    acc[mi][0] = __builtin_amdgcn_mfma_f32_16x16x32_bf16(areg, b##S##0, acc[mi][0], 0, 0, 0); \
    acc[mi][1] = __builtin_amdgcn_mfma_f32_16x16x32_bf16(areg, b##S##1, acc[mi][1], 0, 0, 0); \
    acc[mi][2] = __builtin_amdgcn_mfma_f32_16x16x32_bf16(areg, b##S##2, acc[mi][2], 0, 0, 0); \
    acc[mi][3] = __builtin_amdgcn_mfma_f32_16x16x32_bf16(areg, b##S##3, acc[mi][3], 0, 0, 0);

    // Slice s: CS = s&3 (own slot, A rows 4..7 read here), RS = (s+1)&3
    // (prefetch next slice into NXT set), SS = (s+3)&3 (stage target).
    // Cluster consumes CUR set (prefetched last slice) + x4..x7; zero waits
    // at cluster start for rows 0..3; x4..7's counted wait lands inside.
#define TILE(CS, RS, SS, CUR, NXT, DOSTG, kkst, VMW) do { \
    bf16x8 x4 = LDA(CS, 4), x5 = LDA(CS, 5), x6 = LDA(CS, 6), x7 = LDA(CS, 7); \
    b##NXT##0 = LDB(RS, 0); b##NXT##1 = LDB(RS, 1); \
    b##NXT##2 = LDB(RS, 2); b##NXT##3 = LDB(RS, 3); \
    a##NXT##0 = LDA(RS, 0); a##NXT##1 = LDA(RS, 1); \
    a##NXT##2 = LDA(RS, 2); a##NXT##3 = LDA(RS, 3); \
    if (DOSTG) { STAGE_A(SS, kkst); STAGE_B(SS, kkst); } \
    __builtin_amdgcn_sched_barrier(0); \
    __builtin_amdgcn_s_setprio(1); \
    MROW(0, a##CUR##0, CUR) MROW(1, a##CUR##1, CUR) \
    MROW(2, a##CUR##2, CUR) MROW(3, a##CUR##3, CUR) \
    MROW(4, x4, CUR) MROW(5, x5, CUR) MROW(6, x6, CUR) MROW(7, x7, CUR) \
    __builtin_amdgcn_s_setprio(0); \
    __builtin_amdgcn_sched_barrier(0); \
    asm volatile(VMW); \
    __builtin_amdgcn_s_barrier(); \
    __builtin_amdgcn_sched_barrier(0); \
} while (0)

    // Prologue: stage slots 0,1,2; vmcnt(4) completes slots 0,1; publish;
    // prefetch slice 0 (set E) from slot 0.
    STAGE_A(0, 0);  STAGE_B(0, 0);
    STAGE_A(1, 32); STAGE_B(1, 32);
    STAGE_A(2, 64); STAGE_B(2, 64);
    asm volatile("s_waitcnt vmcnt(4)");
    __builtin_amdgcn_s_barrier();
    __builtin_amdgcn_sched_barrier(0);
    bE0 = LDB(0, 0); bE1 = LDB(0, 1); bE2 = LDB(0, 2); bE3 = LDB(0, 3);
    aE0 = LDA(0, 0); aE1 = LDA(0, 1); aE2 = LDA(0, 2); aE3 = LDA(0, 3);

    // Steady state: slices 0..123 (stage targets 3..126), vmcnt(4)/slice.
#pragma unroll 1
    for (int s4 = 0; s4 < 124; s4 += 4) {
        const int kkb = (s4 + 3) * 32;
        TILE(0, 1, 3, E, O, 1, kkb,       "s_waitcnt vmcnt(4)");
        TILE(1, 2, 0, O, E, 1, kkb + 32,  "s_waitcnt vmcnt(4)");
        TILE(2, 3, 1, E, O, 1, kkb + 64,  "s_waitcnt vmcnt(4)");
        TILE(3, 0, 2, O, E, 1, kkb + 96,  "s_waitcnt vmcnt(4)");
    }

    // Tail: s=124 stages the last slice (127); then drain 4 -> 0.
    TILE(0, 1, 3, E, O, 1, 127 * 32, "s_waitcnt vmcnt(4)");  // s=124
    TILE(1, 2, 0, O, E, 0, 0,        "s_waitcnt vmcnt(0)");  // s=125
    TILE(2, 3, 0, E, O, 0, 0,        "s_nop 0");             // s=126
    {   // s=127: final cluster, consumes O + in-slice rows 4..7 from slot 3.
        bf16x8 x4 = LDA(3, 4), x5 = LDA(3, 5), x6 = LDA(3, 6), x7 = LDA(3, 7);
        __builtin_amdgcn_s_setprio(1);
        MROW(0, aO0, O) MROW(1, aO1, O) MROW(2, aO2, O) MROW(3, aO3, O)
        MROW(4, x4, O) MROW(5, x5, O) MROW(6, x6, O) MROW(7, x7, O)
        __builtin_amdgcn_s_setprio(0);
    }

#undef TILE
#undef MROW
#undef LDA
#undef LDB
#undef STAGE_A
#undef STAGE_B

    // Epilogue. C/D layout (m89/m91-verified): col = lane&15, row = quad*4+reg.
#pragma unroll
    for (int mi = 0; mi < 8; ++mi) {
#pragma unroll
        for (int ni = 0; ni < 4; ++ni) {
            const int r = row0 + wm * 128 + mi * 16 + quad * 4;
            const int c = col0 + wn * 64 + ni * 16 + r16;
#pragma unroll
            for (int i = 0; i < 4; ++i)
                C[(size_t)(r + i) * N_TOTAL + c] = acc[mi][ni][i];
        }
    }
}

// ---------------------------------------------------------------------------
extern "C" void kernel_launch(void* const* d_in, const int* in_sizes, int n_in,
                              void* d_out, int out_size, void* d_ws, size_t ws_size,
                              hipStream_t stream) {
    const float* x      = (const float*)d_in[0];   // [4,2048,4096] fp32
    const int*   packed = (const int*)d_in[1];     // [4096,2048] int32
    const float* scales = (const float*)d_in[2];   // [4096,1] fp32
    const float* ortho  = (const float*)d_in[3];   // [4096,4096] fp32
    float*       out    = (float*)d_out;           // [4,2048,4096] fp32

    // Workspace layout: Xb (bf16, 64 MB) | Wb (bf16, 32 MB) = 96 MB total
    unsigned short* Xb = (unsigned short*)d_ws;
    unsigned short* Wb = (unsigned short*)((char*)d_ws + (size_t)M_TOTAL * K_TOTAL * 2);

    prep_kernel<<<CVT_BLOCKS + DEQ_BLOCKS, 256, 0, stream>>>(x, packed, scales, ortho, Xb, Wb);

    dim3 grid(N_TOTAL / 256, M_TOTAL / 256);  // (16, 32) = 512 blocks
    gemm256_kernel<<<grid, 512, 0, stream>>>(Xb, Wb, out);
}